// Round 3
// baseline (702.589 us; speedup 1.0000x reference)
//
#include <hip/hip_runtime.h>
#include <hip/hip_bf16.h>

typedef _Float16 f16x8 __attribute__((ext_vector_type(8)));
typedef float f32x4 __attribute__((ext_vector_type(4)));

__device__ __forceinline__ void async16(const _Float16* g, _Float16* l) {
  __builtin_amdgcn_global_load_lds(
      (const __attribute__((address_space(1))) unsigned int*)g,
      (__attribute__((address_space(3))) unsigned int*)l, 16, 0, 0);
}

__device__ __forceinline__ float tanh_fast(float x) {
  float e = __expf(2.0f * x);
  return 1.0f - 2.0f * __builtin_amdgcn_rcpf(e + 1.0f);
}
__device__ __forceinline__ float sigmoid_fast(float x) {
  return __builtin_amdgcn_rcpf(1.0f + __expf(-x));
}

// ---------------- K0: transpose + fp32 -> fp16 convert ----------------
__global__ __launch_bounds__(256) void transpose_cvt(const float* __restrict__ in,
                                                     _Float16* __restrict__ out,
                                                     int R, int C) {
  __shared__ float tile[32][33];
  int z = blockIdx.z;
  in  += (size_t)z * R * C;
  out += (size_t)z * R * C;
  int r0 = blockIdx.x * 32, c0 = blockIdx.y * 32;
  int t = threadIdx.x;
  int cc = t & 31, rr8 = t >> 5;
#pragma unroll
  for (int p = 0; p < 4; ++p) {
    int r = rr8 + p * 8;
    tile[cc][r] = in[(size_t)(r0 + r) * C + c0 + cc];
  }
  __syncthreads();
  int rr = t & 31, cc8 = t >> 5;
#pragma unroll
  for (int p = 0; p < 4; ++p) {
    int c = cc8 + p * 8;
    out[(size_t)(c0 + c) * R + r0 + rr] = (_Float16)tile[c][rr];
  }
}

// ---------------- K1: ripple layer 1 ----------------
__global__ __launch_bounds__(256) void k1_ripple1(
    const float* __restrict__ state, const float* __restrict__ action,
    const _Float16* __restrict__ v1t, const float* __restrict__ b1,
    const float* __restrict__ g1, _Float16* __restrict__ x1, int gro) {
  __shared__ __align__(16) _Float16 As[128 * 40];
  int bn = blockIdx.x, bm = blockIdx.y;
  int t = threadIdx.x, w = t >> 6, l = t & 63, q = l >> 4, l15 = l & 15;
  int n0 = bn * 128, m0 = bm * 128;

  {  // stage sa tile [128][32] fp16 (concat state|action)
    int r = t >> 1, half = t & 1;
    size_t grow = (size_t)(gro + m0 + r);
    float v[16];
    if (half == 0) {
      const float4* sp = (const float4*)(state + grow * 24);
      ((float4*)v)[0] = sp[0]; ((float4*)v)[1] = sp[1];
      ((float4*)v)[2] = sp[2]; ((float4*)v)[3] = sp[3];
    } else {
      const float4* sp = (const float4*)(state + grow * 24 + 16);
      ((float4*)v)[0] = sp[0]; ((float4*)v)[1] = sp[1];
      const float4* ap = (const float4*)(action + grow * 8);
      ((float4*)v)[2] = ap[0]; ((float4*)v)[3] = ap[1];
    }
    f16x8 h0, h1;
#pragma unroll
    for (int j = 0; j < 8; ++j) { h0[j] = (_Float16)v[j]; h1[j] = (_Float16)v[8 + j]; }
    *(f16x8*)&As[r * 40 + half * 16] = h0;
    *(f16x8*)&As[r * 40 + half * 16 + 8] = h1;
  }
  __syncthreads();

  int wr = w >> 1, wc = w & 1;
  f16x8 af[4], bf[4];
#pragma unroll
  for (int mi = 0; mi < 4; ++mi)
    af[mi] = *(const f16x8*)&As[(wr * 64 + mi * 16 + l15) * 40 + q * 8];
#pragma unroll
  for (int ni = 0; ni < 4; ++ni)
    bf[ni] = *(const f16x8*)(v1t + (size_t)(n0 + wc * 64 + ni * 16 + l15) * 32 + q * 8);

  f32x4 acc[4][4] = {};
#pragma unroll
  for (int mi = 0; mi < 4; ++mi)
#pragma unroll
    for (int ni = 0; ni < 4; ++ni)
      acc[mi][ni] = __builtin_amdgcn_mfma_f32_16x16x32_f16(af[mi], bf[ni], acc[mi][ni], 0, 0, 0);

#pragma unroll
  for (int ni = 0; ni < 4; ++ni) {
    int col = n0 + wc * 64 + ni * 16 + l15;
    float sg = sigmoid_fast(g1[col >> 5]);
    float bias = b1[col];
#pragma unroll
    for (int mi = 0; mi < 4; ++mi)
#pragma unroll
      for (int r = 0; r < 4; ++r) {
        int row = m0 + wr * 64 + mi * 16 + q * 4 + r;
        x1[(size_t)row * 1024 + col] = (_Float16)(tanh_fast(acc[mi][ni][r] + bias) * sg);
      }
  }
}

// ---------------- K2: ripple layer 2 (the big GEMM) ----------------
// Block tile 128x128 (m97 sweet spot), 2x2 waves of 64x64, acc[4][4] -> ~144
// regs -> 3 waves/SIMD. XCD-affine remap: all 8 bn of one bm on one XCD.
__global__ __launch_bounds__(256, 3) void k2_ripple2(
    const _Float16* __restrict__ x1, const _Float16* __restrict__ v2t,
    const float* __restrict__ b2, const float* __restrict__ g2,
    _Float16* __restrict__ x2, int nbm) {
  __shared__ __align__(16) _Float16 As[128 * 32];   // 8 KB
  __shared__ __align__(16) _Float16 Bs[128 * 32];   // 8 KB
  int g = blockIdx.x;
  int bn, bm;
  if ((nbm & 7) == 0) {          // XCD g%8 gets all 8 bn of bm = x + 8*(j>>3)
    int x = g & 7, j = g >> 3;
    bn = j & 7; bm = x + 8 * (j >> 3);
  } else { bn = g & 7; bm = g >> 3; }
  int t = threadIdx.x, w = t >> 6, l = t & 63, q = l >> 4, l15 = l & 15;
  int n0 = bn * 128, m0 = bm * 128;
  int wr = w >> 1, wc = w & 1;
  f32x4 acc[4][4] = {};

  // staging: 512 chunks of 16B per matrix; thread t owns chunks t and t+256.
  // physical chunk c holds logical (row c>>2, part (c&3)^((c>>3)&3))
  int c0 = t, c1 = t + 256;
  const _Float16* aS0 = x1 + (size_t)(m0 + (c0 >> 2)) * 1024 + ((c0 & 3) ^ ((c0 >> 3) & 3)) * 8;
  const _Float16* aS1 = x1 + (size_t)(m0 + (c1 >> 2)) * 1024 + ((c1 & 3) ^ ((c1 >> 3) & 3)) * 8;
  const _Float16* bS0 = v2t + (size_t)(n0 + (c0 >> 2)) * 1024 + ((c0 & 3) ^ ((c0 >> 3) & 3)) * 8;
  const _Float16* bS1 = v2t + (size_t)(n0 + (c1 >> 2)) * 1024 + ((c1 & 3) ^ ((c1 >> 3) & 3)) * 8;
  _Float16* aD0 = As + c0 * 8; _Float16* aD1 = As + c1 * 8;
  _Float16* bD0 = Bs + c0 * 8; _Float16* bD1 = Bs + c1 * 8;
  int qs = q ^ ((l15 >> 1) & 3);

  for (int kt = 0; kt < 32; ++kt) {
    __syncthreads();
    int ko = kt * 32;
    async16(aS0 + ko, aD0);
    async16(aS1 + ko, aD1);
    async16(bS0 + ko, bD0);
    async16(bS1 + ko, bD1);
    __builtin_amdgcn_s_waitcnt(0);
    __syncthreads();
    f16x8 af[4], bf[4];
#pragma unroll
    for (int mi = 0; mi < 4; ++mi)
      af[mi] = *(const f16x8*)&As[(wr * 64 + mi * 16 + l15) * 32 + qs * 8];
#pragma unroll
    for (int ni = 0; ni < 4; ++ni)
      bf[ni] = *(const f16x8*)&Bs[(wc * 64 + ni * 16 + l15) * 32 + qs * 8];
#pragma unroll
    for (int mi = 0; mi < 4; ++mi)
#pragma unroll
      for (int ni = 0; ni < 4; ++ni)
        acc[mi][ni] = __builtin_amdgcn_mfma_f32_16x16x32_f16(af[mi], bf[ni], acc[mi][ni], 0, 0, 0);
  }

#pragma unroll
  for (int ni = 0; ni < 4; ++ni) {
    int col = n0 + wc * 64 + ni * 16 + l15;
    float sg = sigmoid_fast(g2[col >> 5]);
    float bias = b2[col];
#pragma unroll
    for (int mi = 0; mi < 4; ++mi)
#pragma unroll
      for (int r = 0; r < 4; ++r) {
        int row = m0 + wr * 64 + mi * 16 + q * 4 + r;
        x2[(size_t)row * 1024 + col] = (_Float16)(tanh_fast(acc[mi][ni][r] + bias) * sg);
      }
  }
}

// ---------------- K3: fused q-network head ----------------
// GEMM3 K-chunk = 64 via two 32-K sub-buffers (proven swizzle), halving the
// barrier-drain count from 32 to 16.
__global__ __launch_bounds__(256) void k3_head(
    const _Float16* __restrict__ x2, const _Float16* __restrict__ t1t,
    const _Float16* __restrict__ t2t,
    const float* __restrict__ bq1, const float* __restrict__ ln1g, const float* __restrict__ ln1b,
    const float* __restrict__ bq2, const float* __restrict__ ln2g, const float* __restrict__ ln2b,
    const float* __restrict__ wq3, const float* __restrict__ bq3,
    float* __restrict__ out) {
  __shared__ __align__(16) _Float16 Ast[2 * 64 * 32];    // 8 KB
  __shared__ __align__(16) _Float16 Bst[2 * 256 * 32];   // 32 KB
  __shared__ __align__(16) _Float16 y1h[64 * 264];       // 33 KB
  __shared__ float redA[64 * 4], redB[64 * 4];
  __shared__ float meanv[64], rstdv[64];
  int bm = blockIdx.x;
  int t = threadIdx.x, w = t >> 6, l = t & 63, q = l >> 4, l15 = l & 15;
  int m0 = bm * 64;
  int qs = q ^ ((l15 >> 1) & 3);

  // ---- GEMM3: [64 x 1024] @ [1024 x 256]; wave w owns cols w*64..w*64+63
  f32x4 acc[4][4] = {};
  int cA = t;  // 256 chunks per 64x32 sub-buffer
  const _Float16* aS = x2 + (size_t)(m0 + (cA >> 2)) * 1024 + ((cA & 3) ^ ((cA >> 3) & 3)) * 8;
  _Float16* aD = Ast + cA * 8;
  const _Float16* bS[4]; _Float16* bD[4];
#pragma unroll
  for (int i = 0; i < 4; ++i) {
    int c = t + i * 256;  // 1024 chunks per 256x32 sub-buffer
    bS[i] = t1t + (size_t)(c >> 2) * 1024 + ((c & 3) ^ ((c >> 3) & 3)) * 8;
    bD[i] = Bst + c * 8;
  }

  for (int kt = 0; kt < 16; ++kt) {
    __syncthreads();
    int ko = kt * 64;
    async16(aS + ko, aD);
    async16(aS + ko + 32, aD + 64 * 32);
#pragma unroll
    for (int i = 0; i < 4; ++i) {
      async16(bS[i] + ko, bD[i]);
      async16(bS[i] + ko + 32, bD[i] + 256 * 32);
    }
    __builtin_amdgcn_s_waitcnt(0);
    __syncthreads();
#pragma unroll
    for (int s = 0; s < 2; ++s) {
      f16x8 af[4], bf[4];
#pragma unroll
      for (int mi = 0; mi < 4; ++mi)
        af[mi] = *(const f16x8*)&Ast[s * 2048 + (mi * 16 + l15) * 32 + qs * 8];
#pragma unroll
      for (int ni = 0; ni < 4; ++ni)
        bf[ni] = *(const f16x8*)&Bst[s * 8192 + (w * 64 + ni * 16 + l15) * 32 + qs * 8];
#pragma unroll
      for (int mi = 0; mi < 4; ++mi)
#pragma unroll
        for (int ni = 0; ni < 4; ++ni)
          acc[mi][ni] = __builtin_amdgcn_mfma_f32_16x16x32_f16(af[mi], bf[ni], acc[mi][ni], 0, 0, 0);
    }
  }

  // bias + row-sum / row-sumsq over 256 cols
#pragma unroll
  for (int ni = 0; ni < 4; ++ni) {
    int col = w * 64 + ni * 16 + l15;
    float b = bq1[col];
#pragma unroll
    for (int mi = 0; mi < 4; ++mi)
#pragma unroll
      for (int r = 0; r < 4; ++r) acc[mi][ni][r] += b;
  }
#pragma unroll
  for (int mi = 0; mi < 4; ++mi)
#pragma unroll
    for (int r = 0; r < 4; ++r) {
      int row = mi * 16 + q * 4 + r;
      float s = 0.f, sq = 0.f;
#pragma unroll
      for (int ni = 0; ni < 4; ++ni) { float v = acc[mi][ni][r]; s += v; sq += v * v; }
#pragma unroll
      for (int off = 1; off < 16; off <<= 1) { s += __shfl_xor(s, off); sq += __shfl_xor(sq, off); }
      if (l15 == 0) { redA[row * 4 + w] = s; redB[row * 4 + w] = sq; }
    }
  __syncthreads();
  if (t < 64) {
    float s  = redA[t * 4] + redA[t * 4 + 1] + redA[t * 4 + 2] + redA[t * 4 + 3];
    float sq = redB[t * 4] + redB[t * 4 + 1] + redB[t * 4 + 2] + redB[t * 4 + 3];
    float mean = s * (1.0f / 256.0f);
    float var = sq * (1.0f / 256.0f) - mean * mean;
    meanv[t] = mean; rstdv[t] = rsqrtf(var + 1e-5f);
  }
  __syncthreads();
  // LN + relu -> y1h (fp16, A-layout, padded stride 264)
#pragma unroll
  for (int mi = 0; mi < 4; ++mi)
#pragma unroll
    for (int ni = 0; ni < 4; ++ni)
#pragma unroll
      for (int r = 0; r < 4; ++r) {
        int row = mi * 16 + q * 4 + r;
        int col = w * 64 + ni * 16 + l15;
        float y = (acc[mi][ni][r] - meanv[row]) * rstdv[row] * ln1g[col] + ln1b[col];
        y = fmaxf(y, 0.f);
        y1h[row * 264 + col] = (_Float16)y;
      }
  __syncthreads();

  // ---- GEMM4: [64 x 256] @ [256 x 128]; waves as 2(rows) x 2(cols)
  int wr = w >> 1, wc = w & 1;
  f32x4 a2[2][4] = {};
  for (int kt = 0; kt < 8; ++kt) {
    f16x8 af2[2];
#pragma unroll
    for (int mi = 0; mi < 2; ++mi)
      af2[mi] = *(const f16x8*)&y1h[(wr * 32 + mi * 16 + l15) * 264 + kt * 32 + q * 8];
#pragma unroll
    for (int ni = 0; ni < 4; ++ni) {
      f16x8 bf = *(const f16x8*)(t2t + (size_t)(wc * 64 + ni * 16 + l15) * 256 + kt * 32 + q * 8);
#pragma unroll
      for (int mi = 0; mi < 2; ++mi)
        a2[mi][ni] = __builtin_amdgcn_mfma_f32_16x16x32_f16(af2[mi], bf, a2[mi][ni], 0, 0, 0);
    }
  }
#pragma unroll
  for (int ni = 0; ni < 4; ++ni) {
    int col = wc * 64 + ni * 16 + l15;
    float b = bq2[col];
#pragma unroll
    for (int mi = 0; mi < 2; ++mi)
#pragma unroll
      for (int r = 0; r < 4; ++r) a2[mi][ni][r] += b;
  }
  __syncthreads();
#pragma unroll
  for (int mi = 0; mi < 2; ++mi)
#pragma unroll
    for (int r = 0; r < 4; ++r) {
      int row = wr * 32 + mi * 16 + q * 4 + r;
      float s = 0.f, sq = 0.f;
#pragma unroll
      for (int ni = 0; ni < 4; ++ni) { float v = a2[mi][ni][r]; s += v; sq += v * v; }
#pragma unroll
      for (int off = 1; off < 16; off <<= 1) { s += __shfl_xor(s, off); sq += __shfl_xor(sq, off); }
      if (l15 == 0) { redA[row * 2 + wc] = s; redB[row * 2 + wc] = sq; }
    }
  __syncthreads();
  if (t < 64) {
    float s = redA[t * 2] + redA[t * 2 + 1];
    float sq = redB[t * 2] + redB[t * 2 + 1];
    float mean = s * (1.0f / 128.0f);
    float var = sq * (1.0f / 128.0f) - mean * mean;
    meanv[t] = mean; rstdv[t] = rsqrtf(var + 1e-5f);
  }
  __syncthreads();
  // LN + relu + dot(wq3)
#pragma unroll
  for (int mi = 0; mi < 2; ++mi)
#pragma unroll
    for (int r = 0; r < 4; ++r) {
      int row = wr * 32 + mi * 16 + q * 4 + r;
      float pr = 0.f;
#pragma unroll
      for (int ni = 0; ni < 4; ++ni) {
        int col = wc * 64 + ni * 16 + l15;
        float y = (a2[mi][ni][r] - meanv[row]) * rstdv[row] * ln2g[col] + ln2b[col];
        y = fmaxf(y, 0.f);
        pr += y * wq3[col];
      }
#pragma unroll
      for (int off = 1; off < 16; off <<= 1) pr += __shfl_xor(pr, off);
      if (l15 == 0) redA[row * 2 + wc] = pr;
    }
  __syncthreads();
  if (t < 64) out[m0 + t] = redA[t * 2] + redA[t * 2 + 1] + bq3[0];
}

// ---------------- launcher ----------------
extern "C" void kernel_launch(void* const* d_in, const int* in_sizes, int n_in,
                              void* d_out, int out_size, void* d_ws, size_t ws_size,
                              hipStream_t stream) {
  const float* state  = (const float*)d_in[0];
  const float* action = (const float*)d_in[1];
  const float* W1  = (const float*)d_in[2];
  const float* b1  = (const float*)d_in[3];
  const float* g1  = (const float*)d_in[4];
  const float* W2  = (const float*)d_in[5];
  const float* b2  = (const float*)d_in[6];
  const float* g2  = (const float*)d_in[7];
  const float* Wq1 = (const float*)d_in[8];
  const float* bq1 = (const float*)d_in[9];
  const float* ln1g = (const float*)d_in[10];
  const float* ln1b = (const float*)d_in[11];
  const float* Wq2 = (const float*)d_in[12];
  const float* bq2 = (const float*)d_in[13];
  const float* ln2g = (const float*)d_in[14];
  const float* ln2b = (const float*)d_in[15];
  const float* Wq3 = (const float*)d_in[16];
  const float* bq3 = (const float*)d_in[17];
  int B = in_sizes[0] / 24;

  char* ws = (char*)d_ws;
  _Float16* V1t = (_Float16*)(ws);
  _Float16* V2t = (_Float16*)(ws + 65536);
  _Float16* T1t = (_Float16*)(ws + 65536 + 2097152);
  _Float16* T2t = (_Float16*)(ws + 65536 + 2097152 + 524288);
  size_t woff = (65536 + 2097152 + 524288 + 65536 + 4095) & ~(size_t)4095;

  size_t avail = ws_size > woff ? ws_size - woff : 0;
  long rows = (long)(avail / 4096);
  if (rows > 32768) rows = 32768;
  rows &= ~127L;
  if (rows < 128) rows = 128;
  int S = (int)rows;
  _Float16* x1 = (_Float16*)(ws + woff);
  _Float16* x2 = x1 + (size_t)S * 1024;

  transpose_cvt<<<dim3(1, 1, 32), 256, 0, stream>>>(W1, V1t, 32, 32);
  transpose_cvt<<<dim3(32, 1, 32), 256, 0, stream>>>(W2, V2t, 1024, 32);
  transpose_cvt<<<dim3(32, 8, 1), 256, 0, stream>>>(Wq1, T1t, 1024, 256);
  transpose_cvt<<<dim3(8, 4, 1), 256, 0, stream>>>(Wq2, T2t, 256, 128);

  for (int r0 = 0; r0 < B; r0 += S) {
    int Sc = S < (B - r0) ? S : (B - r0);
    int nbm = Sc / 128;
    k1_ripple1<<<dim3(8, nbm), 256, 0, stream>>>(state, action, V1t, b1, g1, x1, r0);
    k2_ripple2<<<dim3(8 * nbm), 256, 0, stream>>>(x1, V2t, b2, g2, x2, nbm);
    k3_head<<<dim3(Sc / 64), 256, 0, stream>>>(x2, T1t, T2t, bq1, ln1g, ln1b,
                                               bq2, ln2g, ln2b, Wq3, bq3,
                                               (float*)d_out + r0);
  }
}

// Round 4
// 694.353 us; speedup vs baseline: 1.0119x; 1.0119x over previous
//
#include <hip/hip_runtime.h>
#include <hip/hip_bf16.h>

typedef _Float16 f16x8 __attribute__((ext_vector_type(8)));
typedef float f32x4 __attribute__((ext_vector_type(4)));

__device__ __forceinline__ void async16(const _Float16* g, _Float16* l) {
  __builtin_amdgcn_global_load_lds(
      (const __attribute__((address_space(1))) unsigned int*)g,
      (__attribute__((address_space(3))) unsigned int*)l, 16, 0, 0);
}

__device__ __forceinline__ float tanh_fast(float x) {
  float e = __expf(2.0f * x);
  return 1.0f - 2.0f * __builtin_amdgcn_rcpf(e + 1.0f);
}
__device__ __forceinline__ float sigmoid_fast(float x) {
  return __builtin_amdgcn_rcpf(1.0f + __expf(-x));
}

// ---------------- K0: all 4 weight transposes in one dispatch ----------------
// each 32x32 tile: in [R][C] fp32 -> out [C][R] fp16
__global__ __launch_bounds__(256) void transpose_all(
    const float* __restrict__ W1, const float* __restrict__ W2,
    const float* __restrict__ Wq1, const float* __restrict__ Wq2,
    _Float16* __restrict__ V1t, _Float16* __restrict__ V2t,
    _Float16* __restrict__ T1t, _Float16* __restrict__ T2t) {
  __shared__ float tile[32][33];
  int b = blockIdx.x;
  const float* in; _Float16* out; int R, C, rt, ct;
  if (b < 32) {                    // W1: 32 x (32x32)
    in = W1 + b * 1024; out = V1t + b * 1024; R = 32; C = 32; rt = 0; ct = 0;
  } else if (b < 32 + 1024) {      // W2: 32 x (1024x32)
    int i = b - 32; int z = i >> 5;
    in = W2 + (size_t)z * 32768; out = V2t + (size_t)z * 32768;
    R = 1024; C = 32; rt = i & 31; ct = 0;
  } else if (b < 32 + 1024 + 256) {  // Wq1: 1024x256
    int i = b - 1056; in = Wq1; out = T1t; R = 1024; C = 256; rt = i >> 3; ct = i & 7;
  } else {                         // Wq2: 256x128
    int i = b - 1312; in = Wq2; out = T2t; R = 256; C = 128; rt = i >> 2; ct = i & 3;
  }
  int r0 = rt * 32, c0 = ct * 32;
  int t = threadIdx.x;
  int cc = t & 31, rr8 = t >> 5;
#pragma unroll
  for (int p = 0; p < 4; ++p) {
    int r = rr8 + p * 8;
    tile[cc][r] = in[(size_t)(r0 + r) * C + c0 + cc];
  }
  __syncthreads();
  int rr = t & 31, cc8 = t >> 5;
#pragma unroll
  for (int p = 0; p < 4; ++p) {
    int c = cc8 + p * 8;
    out[(size_t)(c0 + c) * R + r0 + rr] = (_Float16)tile[c][rr];
  }
}

// ---------------- K1: ripple layer 1 ----------------
__global__ __launch_bounds__(256) void k1_ripple1(
    const float* __restrict__ state, const float* __restrict__ action,
    const _Float16* __restrict__ v1t, const float* __restrict__ b1,
    const float* __restrict__ g1, _Float16* __restrict__ x1, int gro) {
  __shared__ __align__(16) _Float16 As[128 * 40];
  int bn = blockIdx.x, bm = blockIdx.y;
  int t = threadIdx.x, w = t >> 6, l = t & 63, q = l >> 4, l15 = l & 15;
  int n0 = bn * 128, m0 = bm * 128;

  {  // stage sa tile [128][32] fp16 (concat state|action)
    int r = t >> 1, half = t & 1;
    size_t grow = (size_t)(gro + m0 + r);
    float v[16];
    if (half == 0) {
      const float4* sp = (const float4*)(state + grow * 24);
      ((float4*)v)[0] = sp[0]; ((float4*)v)[1] = sp[1];
      ((float4*)v)[2] = sp[2]; ((float4*)v)[3] = sp[3];
    } else {
      const float4* sp = (const float4*)(state + grow * 24 + 16);
      ((float4*)v)[0] = sp[0]; ((float4*)v)[1] = sp[1];
      const float4* ap = (const float4*)(action + grow * 8);
      ((float4*)v)[2] = ap[0]; ((float4*)v)[3] = ap[1];
    }
    f16x8 h0, h1;
#pragma unroll
    for (int j = 0; j < 8; ++j) { h0[j] = (_Float16)v[j]; h1[j] = (_Float16)v[8 + j]; }
    *(f16x8*)&As[r * 40 + half * 16] = h0;
    *(f16x8*)&As[r * 40 + half * 16 + 8] = h1;
  }
  __syncthreads();

  int wr = w >> 1, wc = w & 1;
  f16x8 af[4], bf[4];
#pragma unroll
  for (int mi = 0; mi < 4; ++mi)
    af[mi] = *(const f16x8*)&As[(wr * 64 + mi * 16 + l15) * 40 + q * 8];
#pragma unroll
  for (int ni = 0; ni < 4; ++ni)
    bf[ni] = *(const f16x8*)(v1t + (size_t)(n0 + wc * 64 + ni * 16 + l15) * 32 + q * 8);

  f32x4 acc[4][4] = {};
#pragma unroll
  for (int mi = 0; mi < 4; ++mi)
#pragma unroll
    for (int ni = 0; ni < 4; ++ni)
      acc[mi][ni] = __builtin_amdgcn_mfma_f32_16x16x32_f16(af[mi], bf[ni], acc[mi][ni], 0, 0, 0);

  // epilogue: pack via LDS (reuse As), coalesced dwordx4 stores; 4 passes of 32 cols
  for (int ni = 0; ni < 4; ++ni) {
    __syncthreads();
    int col = n0 + wc * 64 + ni * 16 + l15;
    float sg = sigmoid_fast(g1[col >> 5]);
    float bias = b1[col];
    int cl = wc * 16 + l15;
#pragma unroll
    for (int mi = 0; mi < 4; ++mi)
#pragma unroll
      for (int r = 0; r < 4; ++r) {
        int rl = wr * 64 + mi * 16 + q * 4 + r;
        As[rl * 40 + cl] = (_Float16)(tanh_fast(acc[mi][ni][r] + bias) * sg);
      }
    __syncthreads();
#pragma unroll
    for (int i = 0; i < 2; ++i) {
      int c = t + i * 256;
      int row = c >> 2, sub = c & 3;
      int colg = n0 + (sub >> 1) * 64 + ni * 16 + (sub & 1) * 8;
      *(float4*)(x1 + (size_t)(m0 + row) * 1024 + colg) = *(const float4*)&As[row * 40 + sub * 8];
    }
  }
}

// ---------------- K2: ripple layer 2 (the big GEMM) ----------------
// 128x128 tile, 2x2 waves of 64x64. XOR-swizzled LDS; XCD-affine remap.
// Epilogue packs via LDS -> dwordx4 stores.
__global__ __launch_bounds__(256, 4) void k2_ripple2(
    const _Float16* __restrict__ x1, const _Float16* __restrict__ v2t,
    const float* __restrict__ b2, const float* __restrict__ g2,
    _Float16* __restrict__ x2, int nbm) {
  __shared__ __align__(16) _Float16 SMEM[9216];   // staging 16 KB; pack 18 KB
  _Float16* As = SMEM;
  _Float16* Bs = SMEM + 4096;
  int g = blockIdx.x;
  int bn, bm;
  if ((nbm & 7) == 0) {
    int x = g & 7, j = g >> 3;
    bn = j & 7; bm = x + 8 * (j >> 3);
  } else { bn = g & 7; bm = g >> 3; }
  int t = threadIdx.x, w = t >> 6, l = t & 63, q = l >> 4, l15 = l & 15;
  int n0 = bn * 128, m0 = bm * 128;
  int wr = w >> 1, wc = w & 1;
  f32x4 acc[4][4] = {};

  int c0 = t, c1 = t + 256;
  const _Float16* aS0 = x1 + (size_t)(m0 + (c0 >> 2)) * 1024 + ((c0 & 3) ^ ((c0 >> 3) & 3)) * 8;
  const _Float16* aS1 = x1 + (size_t)(m0 + (c1 >> 2)) * 1024 + ((c1 & 3) ^ ((c1 >> 3) & 3)) * 8;
  const _Float16* bS0 = v2t + (size_t)(n0 + (c0 >> 2)) * 1024 + ((c0 & 3) ^ ((c0 >> 3) & 3)) * 8;
  const _Float16* bS1 = v2t + (size_t)(n0 + (c1 >> 2)) * 1024 + ((c1 & 3) ^ ((c1 >> 3) & 3)) * 8;
  _Float16* aD0 = As + c0 * 8; _Float16* aD1 = As + c1 * 8;
  _Float16* bD0 = Bs + c0 * 8; _Float16* bD1 = Bs + c1 * 8;
  int qs = q ^ ((l15 >> 1) & 3);

  for (int kt = 0; kt < 32; ++kt) {
    __syncthreads();
    int ko = kt * 32;
    async16(aS0 + ko, aD0);
    async16(aS1 + ko, aD1);
    async16(bS0 + ko, bD0);
    async16(bS1 + ko, bD1);
    __builtin_amdgcn_s_waitcnt(0);
    __syncthreads();
    f16x8 af[4], bf[4];
#pragma unroll
    for (int mi = 0; mi < 4; ++mi)
      af[mi] = *(const f16x8*)&As[(wr * 64 + mi * 16 + l15) * 32 + qs * 8];
#pragma unroll
    for (int ni = 0; ni < 4; ++ni)
      bf[ni] = *(const f16x8*)&Bs[(wc * 64 + ni * 16 + l15) * 32 + qs * 8];
#pragma unroll
    for (int mi = 0; mi < 4; ++mi)
#pragma unroll
      for (int ni = 0; ni < 4; ++ni)
        acc[mi][ni] = __builtin_amdgcn_mfma_f32_16x16x32_f16(af[mi], bf[ni], acc[mi][ni], 0, 0, 0);
  }

  // epilogue: gate+tanh, pack 128x64 per pass (stride 72), dwordx4 stores
  for (int pass = 0; pass < 2; ++pass) {
    __syncthreads();
#pragma unroll
    for (int ni2 = 0; ni2 < 2; ++ni2) {
      int ni = pass * 2 + ni2;
      int col = n0 + wc * 64 + ni * 16 + l15;
      float sg = sigmoid_fast(g2[col >> 5]);
      float bias = b2[col];
      int cl = wc * 32 + ni2 * 16 + l15;
#pragma unroll
      for (int mi = 0; mi < 4; ++mi)
#pragma unroll
        for (int r = 0; r < 4; ++r) {
          int rl = wr * 64 + mi * 16 + q * 4 + r;
          SMEM[rl * 72 + cl] = (_Float16)(tanh_fast(acc[mi][ni][r] + bias) * sg);
        }
    }
    __syncthreads();
#pragma unroll
    for (int i = 0; i < 4; ++i) {
      int c = t + i * 256;
      int row = c >> 3, sub = c & 7;
      int colg = n0 + (sub >> 2) * 64 + (pass * 2 + ((sub >> 1) & 1)) * 16 + (sub & 1) * 8;
      *(float4*)(x2 + (size_t)(m0 + row) * 1024 + colg) = *(const float4*)&SMEM[row * 72 + sub * 8];
    }
  }
}

// ---------------- K3: fused q-network head ----------------
// M=128, N=256, 512 threads / 8 waves (2 row x 4 col of 64x64).
// y1h LDS unioned with the staging buffers.
__global__ __launch_bounds__(512, 4) void k3_head(
    const _Float16* __restrict__ x2, const _Float16* __restrict__ t1t,
    const _Float16* __restrict__ t2t,
    const float* __restrict__ bq1, const float* __restrict__ ln1g, const float* __restrict__ ln1b,
    const float* __restrict__ bq2, const float* __restrict__ ln2g, const float* __restrict__ ln2b,
    const float* __restrict__ wq3, const float* __restrict__ bq3,
    float* __restrict__ out) {
  __shared__ __align__(16) _Float16 y1h[128 * 264];   // 66 KB; front 24 KB doubles as staging
  __shared__ float redA[128 * 4], redB[128 * 4];
  __shared__ float meanv[128], rstdv[128];
  _Float16* Ast = y1h;           // 128x32 = 4096 hw
  _Float16* Bst = y1h + 4096;    // 256x32 = 8192 hw
  int bm = blockIdx.x;
  int t = threadIdx.x, w = t >> 6, l = t & 63, q = l >> 4, l15 = l & 15;
  int wr = w >> 2, wc = w & 3;   // 2 x 4 wave grid
  int m0 = bm * 128;
  int qs = q ^ ((l15 >> 1) & 3);

  // ---- GEMM3: [128 x 1024] @ [1024 x 256]
  f32x4 acc[4][4] = {};
  const _Float16* aS = x2 + (size_t)(m0 + (t >> 2)) * 1024 + ((t & 3) ^ ((t >> 3) & 3)) * 8;
  _Float16* aD = Ast + t * 8;
  int cb0 = t, cb1 = t + 512;
  const _Float16* bS0 = t1t + (size_t)(cb0 >> 2) * 1024 + ((cb0 & 3) ^ ((cb0 >> 3) & 3)) * 8;
  const _Float16* bS1 = t1t + (size_t)(cb1 >> 2) * 1024 + ((cb1 & 3) ^ ((cb1 >> 3) & 3)) * 8;
  _Float16* bD0 = Bst + cb0 * 8;
  _Float16* bD1 = Bst + cb1 * 8;

  for (int kt = 0; kt < 32; ++kt) {
    __syncthreads();
    int ko = kt * 32;
    async16(aS + ko, aD);
    async16(bS0 + ko, bD0);
    async16(bS1 + ko, bD1);
    __builtin_amdgcn_s_waitcnt(0);
    __syncthreads();
    f16x8 af[4], bf[4];
#pragma unroll
    for (int mi = 0; mi < 4; ++mi)
      af[mi] = *(const f16x8*)&Ast[(wr * 64 + mi * 16 + l15) * 32 + qs * 8];
#pragma unroll
    for (int ni = 0; ni < 4; ++ni)
      bf[ni] = *(const f16x8*)&Bst[(wc * 64 + ni * 16 + l15) * 32 + qs * 8];
#pragma unroll
    for (int mi = 0; mi < 4; ++mi)
#pragma unroll
      for (int ni = 0; ni < 4; ++ni)
        acc[mi][ni] = __builtin_amdgcn_mfma_f32_16x16x32_f16(af[mi], bf[ni], acc[mi][ni], 0, 0, 0);
  }

  // bias + row-sum/sumsq over 256 cols
#pragma unroll
  for (int ni = 0; ni < 4; ++ni) {
    int col = wc * 64 + ni * 16 + l15;
    float b = bq1[col];
#pragma unroll
    for (int mi = 0; mi < 4; ++mi)
#pragma unroll
      for (int r = 0; r < 4; ++r) acc[mi][ni][r] += b;
  }
#pragma unroll
  for (int mi = 0; mi < 4; ++mi)
#pragma unroll
    for (int r = 0; r < 4; ++r) {
      int row = wr * 64 + mi * 16 + q * 4 + r;
      float s = 0.f, sq = 0.f;
#pragma unroll
      for (int ni = 0; ni < 4; ++ni) { float v = acc[mi][ni][r]; s += v; sq += v * v; }
#pragma unroll
      for (int off = 1; off < 16; off <<= 1) { s += __shfl_xor(s, off); sq += __shfl_xor(sq, off); }
      if (l15 == 0) { redA[row * 4 + wc] = s; redB[row * 4 + wc] = sq; }
    }
  __syncthreads();
  if (t < 128) {
    float s  = redA[t * 4] + redA[t * 4 + 1] + redA[t * 4 + 2] + redA[t * 4 + 3];
    float sq = redB[t * 4] + redB[t * 4 + 1] + redB[t * 4 + 2] + redB[t * 4 + 3];
    float mean = s * (1.0f / 256.0f);
    float var = sq * (1.0f / 256.0f) - mean * mean;
    meanv[t] = mean; rstdv[t] = rsqrtf(var + 1e-5f);
  }
  __syncthreads();
  // LN + relu -> y1h (overwrites staging region; all staging reads are done)
#pragma unroll
  for (int mi = 0; mi < 4; ++mi)
#pragma unroll
    for (int ni = 0; ni < 4; ++ni)
#pragma unroll
      for (int r = 0; r < 4; ++r) {
        int row = wr * 64 + mi * 16 + q * 4 + r;
        int col = wc * 64 + ni * 16 + l15;
        float y = (acc[mi][ni][r] - meanv[row]) * rstdv[row] * ln1g[col] + ln1b[col];
        y = fmaxf(y, 0.f);
        y1h[row * 264 + col] = (_Float16)y;
      }
  __syncthreads();

  // ---- GEMM4: [128 x 256] @ [256 x 128]; waves 2(row x64) x 4(col x32)
  f32x4 a2[4][2] = {};
  for (int kt = 0; kt < 8; ++kt) {
    f16x8 af2[4];
#pragma unroll
    for (int mi = 0; mi < 4; ++mi)
      af2[mi] = *(const f16x8*)&y1h[(wr * 64 + mi * 16 + l15) * 264 + kt * 32 + q * 8];
#pragma unroll
    for (int ni = 0; ni < 2; ++ni) {
      f16x8 bf = *(const f16x8*)(t2t + (size_t)(wc * 32 + ni * 16 + l15) * 256 + kt * 32 + q * 8);
#pragma unroll
      for (int mi = 0; mi < 4; ++mi)
        a2[mi][ni] = __builtin_amdgcn_mfma_f32_16x16x32_f16(af2[mi], bf, a2[mi][ni], 0, 0, 0);
    }
  }
#pragma unroll
  for (int ni = 0; ni < 2; ++ni) {
    int col = wc * 32 + ni * 16 + l15;
    float b = bq2[col];
#pragma unroll
    for (int mi = 0; mi < 4; ++mi)
#pragma unroll
      for (int r = 0; r < 4; ++r) a2[mi][ni][r] += b;
  }
  __syncthreads();   // redA/redB reuse
#pragma unroll
  for (int mi = 0; mi < 4; ++mi)
#pragma unroll
    for (int r = 0; r < 4; ++r) {
      int row = wr * 64 + mi * 16 + q * 4 + r;
      float s = 0.f, sq = 0.f;
#pragma unroll
      for (int ni = 0; ni < 2; ++ni) { float v = a2[mi][ni][r]; s += v; sq += v * v; }
#pragma unroll
      for (int off = 1; off < 16; off <<= 1) { s += __shfl_xor(s, off); sq += __shfl_xor(sq, off); }
      if (l15 == 0) { redA[row * 4 + wc] = s; redB[row * 4 + wc] = sq; }
    }
  __syncthreads();
  if (t < 128) {
    float s  = redA[t * 4] + redA[t * 4 + 1] + redA[t * 4 + 2] + redA[t * 4 + 3];
    float sq = redB[t * 4] + redB[t * 4 + 1] + redB[t * 4 + 2] + redB[t * 4 + 3];
    float mean = s * (1.0f / 128.0f);
    float var = sq * (1.0f / 128.0f) - mean * mean;
    meanv[t] = mean; rstdv[t] = rsqrtf(var + 1e-5f);
  }
  __syncthreads();
  // LN + relu + dot(wq3)
#pragma unroll
  for (int mi = 0; mi < 4; ++mi)
#pragma unroll
    for (int r = 0; r < 4; ++r) {
      int row = wr * 64 + mi * 16 + q * 4 + r;
      float pr = 0.f;
#pragma unroll
      for (int ni = 0; ni < 2; ++ni) {
        int col = wc * 32 + ni * 16 + l15;
        float y = (a2[mi][ni][r] - meanv[row]) * rstdv[row] * ln2g[col] + ln2b[col];
        y = fmaxf(y, 0.f);
        pr += y * wq3[col];
      }
#pragma unroll
      for (int off = 1; off < 16; off <<= 1) pr += __shfl_xor(pr, off);
      if (l15 == 0) redA[row * 4 + wc] = pr;
    }
  __syncthreads();
  if (t < 128)
    out[m0 + t] = redA[t * 4] + redA[t * 4 + 1] + redA[t * 4 + 2] + redA[t * 4 + 3] + bq3[0];
}

// ---------------- launcher ----------------
extern "C" void kernel_launch(void* const* d_in, const int* in_sizes, int n_in,
                              void* d_out, int out_size, void* d_ws, size_t ws_size,
                              hipStream_t stream) {
  const float* state  = (const float*)d_in[0];
  const float* action = (const float*)d_in[1];
  const float* W1  = (const float*)d_in[2];
  const float* b1  = (const float*)d_in[3];
  const float* g1  = (const float*)d_in[4];
  const float* W2  = (const float*)d_in[5];
  const float* b2  = (const float*)d_in[6];
  const float* g2  = (const float*)d_in[7];
  const float* Wq1 = (const float*)d_in[8];
  const float* bq1 = (const float*)d_in[9];
  const float* ln1g = (const float*)d_in[10];
  const float* ln1b = (const float*)d_in[11];
  const float* Wq2 = (const float*)d_in[12];
  const float* bq2 = (const float*)d_in[13];
  const float* ln2g = (const float*)d_in[14];
  const float* ln2b = (const float*)d_in[15];
  const float* Wq3 = (const float*)d_in[16];
  const float* bq3 = (const float*)d_in[17];
  int B = in_sizes[0] / 24;

  char* ws = (char*)d_ws;
  _Float16* V1t = (_Float16*)(ws);
  _Float16* V2t = (_Float16*)(ws + 65536);
  _Float16* T1t = (_Float16*)(ws + 65536 + 2097152);
  _Float16* T2t = (_Float16*)(ws + 65536 + 2097152 + 524288);
  size_t woff = (65536 + 2097152 + 524288 + 65536 + 4095) & ~(size_t)4095;

  size_t avail = ws_size > woff ? ws_size - woff : 0;
  int S, G;
  if (avail >= (size_t)32768 * 2048 * 3) {   // x1 (S rows) + x2 (2*S rows)
    S = 32768; G = 2;
  } else {
    long rows = (long)(avail / 4096);        // x1 + x2 (1 slice each)
    if (rows > 32768) rows = 32768;
    rows &= ~127L;
    if (rows < 128) rows = 128;
    S = (int)rows; G = 1;
  }
  _Float16* x1 = (_Float16*)(ws + woff);
  _Float16* x2 = x1 + (size_t)S * 1024;

  transpose_all<<<1344, 256, 0, stream>>>(W1, W2, Wq1, Wq2, V1t, V2t, T1t, T2t);

  int nsl = (B + S - 1) / S;
  for (int i = 0; i < nsl; ++i) {
    int r0 = i * S;
    int Sc = S < (B - r0) ? S : (B - r0);
    int nbm = Sc / 128;
    k1_ripple1<<<dim3(8, nbm), 256, 0, stream>>>(state, action, V1t, b1, g1, x1, r0);
    k2_ripple2<<<dim3(8 * nbm), 256, 0, stream>>>(x1, V2t, b2, g2,
                                                  x2 + (size_t)(i % G) * S * 1024, nbm);
    if (i % G == G - 1 || i == nsl - 1) {
      int gstart = (i - i % G) * S;
      int nrows = r0 + Sc - gstart;
      k3_head<<<dim3(nrows / 128), 512, 0, stream>>>(x2, T1t, T2t, bq1, ln1g, ln1b,
                                                     bq2, ln2g, ln2b, Wq3, bq3,
                                                     (float*)d_out + gstart);
    }
  }
}